// Round 1
// baseline (813.494 us; speedup 1.0000x reference)
//
#include <hip/hip_runtime.h>
#include <math.h>

#define NPART 32
#define ADIM  20
#define ODIM  64
#define HID   256
#define NSTEPS 5
#define LRC   0.1f
#define NBLK  512     // 2 states per block
#define LOG33 3.4965075614664802f
#define A0LD  104     // A0s row stride in shorts: 52 words == 20 mod 32 -> 2-way (free)

typedef short bf8 __attribute__((ext_vector_type(8)));   // 8 bf16 (4 VGPRs)
typedef short s4b __attribute__((ext_vector_type(4)));   // 4 bf16 packed store
typedef float f4  __attribute__((ext_vector_type(4)));   // MFMA C/D
typedef unsigned u4 __attribute__((ext_vector_type(4)));

// workspace layout (bf16 element offsets)
#define OW1T(n) ((n)*24576)             // [256 n][96 k]   w1^T, k-pad 84->96 (fwd L1 B)
#define OW2T(n) (49152 + (n)*65536)     // [256 n][256 k]  w2^T (fwd L2 B)
#define OW2C(n) (180224 + (n)*65536)    // w2 raw rows with w3 folded: w2[n1][k]*w3[k] (bwd dh1 B)
#define OW1X(n) (311296 + (n)*8192)     // [32 d][256 n]   w1 act-rows (score B)
#define WS_ELEMS 327680

__device__ __forceinline__ short f2bf(float x) {          // RNE f32->bf16 (prep only)
    unsigned u = __float_as_uint(x);
    u += 0x7FFFu + ((u >> 16) & 1u);
    return (short)(u >> 16);
}
__device__ __forceinline__ short f2bfT(float x) {         // truncating f32->bf16 (fast)
    return (short)(__float_as_uint(x) >> 16);
}
__device__ __forceinline__ float bf2f(short s) {
    return __uint_as_float(((unsigned)(unsigned short)s) << 16);
}

#define MFMA(a,b,c) __builtin_amdgcn_mfma_f32_16x16x32_bf16((a),(b),(c),0,0,0)

// ---------- prep: build bf16 weight images in ws ----------
__global__ void prep_weights(const float* __restrict__ w1a, const float* __restrict__ w2a,
                             const float* __restrict__ w3a, const float* __restrict__ w1b,
                             const float* __restrict__ w2b, const float* __restrict__ w3b,
                             unsigned short* __restrict__ ws)
{
    int idx = blockIdx.x * 256 + threadIdx.x;
    if (idx >= WS_ELEMS) return;
    float val;
    if (idx < 49152) {
        int net = idx / 24576, rem = idx % 24576;
        int n = rem / 96, k = rem % 96;
        const float* w1 = net ? w1b : w1a;
        val = (k < 84) ? w1[k*256 + n] : 0.f;
    } else if (idx < 180224) {
        int t2 = idx - 49152; int net = t2 / 65536, rem = t2 % 65536;
        int n = rem / 256, k = rem % 256;
        const float* w2 = net ? w2b : w2a;
        val = w2[k*256 + n];
    } else if (idx < 311296) {
        int t2 = idx - 180224; int net = t2 / 65536, rem = t2 % 65536;
        const float* w2 = net ? w2b : w2a;
        const float* w3 = net ? w3b : w3a;
        val = w2[rem] * w3[rem % 256];            // fold w3 into bwd w2 rows (fp32 product)
    } else {
        int t2 = idx - 311296; int net = t2 / 8192, rem = t2 % 8192;
        int d = rem / 256, n = rem % 256;
        const float* w1 = net ? w1b : w1a;
        val = (d < 20) ? w1[(64 + d)*256 + n] : 0.f;
    }
    ws[idx] = (unsigned short)f2bf(val);
}

// ---------- main: 2 states per block, 512 threads ----------
__global__ void __launch_bounds__(512, 4)
svgd_main(const float* __restrict__ obs,  const float* __restrict__ a0g,
          const float* __restrict__ b1a,  const float* __restrict__ b2a, const float* __restrict__ b3a,
          const float* __restrict__ b1b,  const float* __restrict__ b2b, const float* __restrict__ b3b,
          const float* __restrict__ w3af, const float* __restrict__ w3bf,
          const unsigned short* __restrict__ ws, float* __restrict__ out)
{
    __shared__ __align__(16) short A0s[64*A0LD];    // [obs|X|pad] bf16, 2 states stacked
    __shared__ __align__(16) short hbuf[64*264];    // h1/g1 bf16; RBF shadows alias (see below)
    __shared__ unsigned maskS[2][2][64][8];         // relu bitmasks (fully overwritten each step)
    __shared__ float Xm[64*20];                     // fp32 master particles
    __shared__ float scoreS[64*21];
    __shared__ float qpart[2][8][64];
    __shared__ int   winsS[64];
    __shared__ float logps[64];
    __shared__ unsigned short lutI[496], lutJ[496];
    __shared__ float med2[4];                        // [state][2]
    __shared__ float qvS[64];
    __shared__ float normsS[64], rowKS[64];
    __shared__ __align__(16) float diagS[64];
    __shared__ __align__(16) uint2 lutE[16];         // nibble -> 4 bf16 {0,1}; 32 words == 32 banks

    // hbuf alias map (short offsets), lifetimes confined between "g1 dead" and "next h1":
    // d2sF  [2][32 rows][36 f32]  shorts     0.. 4607   (w P2, r P3/P4)
    // GSF   [2][32 rows][36 f32]  shorts  4608.. 9215   (w P2, r P4)
    // SBs   [64 rows][40]  bf16   shorts  9216..11775   (w P1, r P2)  -- dead after P2
    // KbS   [2][32][40]    bf16   shorts  9216..11775   (w P4, r P5)  -- aliases SBs
    // STbS  [2][32 dd][40 j]      shorts 11776..14335   (w P1, r P5)
    // XTbS  [2][32 dd][40 j]      shorts 14336..16895   (w P1, r P5)
    float* d2sF = (float*)hbuf;
    float* GSF  = ((float*)hbuf) + 2304;
    short* SBs  = hbuf + 9216;
    short* KbS  = hbuf + 9216;
    short* STbS = hbuf + 11776;
    short* XTbS = hbuf + 14336;

    const int t = threadIdx.x, b = blockIdx.x;
    const int lane = t & 63, wv = t >> 6;           // 8 waves
    const int q = lane >> 4, mp = lane & 15;
    const int nb = wv * 32;                          // 32-col slice of the 256-wide GEMMs

    // ---- init ----
    for (int p = t; p < 64*ODIM; p += 512) {
        int i = p >> 6, d = p & 63;
        A0s[i*A0LD + d] = f2bfT(obs[(b*64 + i)*ODIM + d]);
    }
    for (int p = t; p < 64*ADIM; p += 512) {
        int i = p / 20, d = p - i*20;
        float v = a0g[(b*64 + i)*20 + d];
        Xm[p] = v;
        A0s[i*A0LD + 64 + d] = f2bfT(v);
    }
    for (int p = t; p < 64*12; p += 512) { int i = p/12, d = p - i*12; A0s[i*A0LD + 84 + d] = 0; }
    if (t < 496) {
        int i_ = 0, rem = t;
        while (rem >= 31 - i_) { rem -= 31 - i_; ++i_; }
        lutI[t] = (unsigned short)i_; lutJ[t] = (unsigned short)(i_ + 1 + rem);
    }
    if (t < 16) {
        lutE[t] = make_uint2(((t & 1) ? 0x3F80u : 0u) | ((t & 2) ? 0x3F800000u : 0u),
                             ((t & 4) ? 0x3F80u : 0u) | ((t & 8) ? 0x3F800000u : 0u));
    }
    if (t < 64) logps[t] = 0.f;
    __syncthreads();

    for (int step = 0; step < NSTEPS; ++step) {
        // ================= forward both nets =================
        for (int net = 0; net < 2; ++net) {
            const unsigned short* w1t = ws + OW1T(net);
            const unsigned short* w2t = ws + OW2T(net);
            const float* b1p = net ? b1b : b1a;
            const float* b2p = net ? b2b : b2a;
            const float* w3p = net ? w3bf : w3af;

            // ---- L1: [64 x 96] @ w1t -> h1 ----
            f4 acc[4][2];
            #pragma unroll
            for (int h = 0; h < 4; ++h) { acc[h][0] = (f4){0,0,0,0}; acc[h][1] = (f4){0,0,0,0}; }
            {
                const unsigned short* bp0 = w1t + (size_t)(nb +      mp)*96 + q*8;
                const unsigned short* bp1 = w1t + (size_t)(nb + 16 + mp)*96 + q*8;
                bf8 bb0 = *(const bf8*)bp0, bb1 = *(const bf8*)bp1;
                #pragma unroll
                for (int k0 = 0; k0 < 96; k0 += 32) {
                    bf8 n0 = bb0, n1 = bb1;
                    if (k0 + 32 < 96) { n0 = *(const bf8*)(bp0 + k0 + 32); n1 = *(const bf8*)(bp1 + k0 + 32); }
                    #pragma unroll
                    for (int h = 0; h < 4; ++h) {
                        bf8 aa = *(const bf8*)&A0s[(h*16 + mp)*A0LD + k0 + q*8];
                        acc[h][0] = MFMA(aa, bb0, acc[h][0]);
                        acc[h][1] = MFMA(aa, bb1, acc[h][1]);
                    }
                    bb0 = n0; bb1 = n1;
                }
            }
            {
                float bias0 = b1p[nb + mp], bias1 = b1p[nb + 16 + mp];
                #pragma unroll
                for (int h = 0; h < 4; ++h) {
                    #pragma unroll
                    for (int r = 0; r < 4; ++r) {
                        float v0 = acc[h][0][r] + bias0;
                        float v1 = acc[h][1][r] + bias1;
                        bool p0 = v0 > 0.f, p1 = v1 > 0.f;
                        unsigned long long bal0 = __ballot(p0);
                        unsigned long long bal1 = __ballot(p1);
                        int row = h*16 + q*4 + r;
                        hbuf[row*264 + nb +      mp] = f2bfT(p0 ? v0 : 0.f);
                        hbuf[row*264 + nb + 16 + mp] = f2bfT(p1 ? v1 : 0.f);
                        if (mp == 0) {
                            unsigned w = (unsigned)((bal0 >> (q*16)) & 0xFFFFull)
                                       | (((unsigned)((bal1 >> (q*16)) & 0xFFFFull)) << 16);
                            maskS[net][0][row][wv] = w;       // single writer, no atomic
                        }
                    }
                }
            }
            __syncthreads();

            // ---- L2: h1 @ w2t (w3/q fused, no h2 materialization) ----
            #pragma unroll
            for (int h = 0; h < 4; ++h) { acc[h][0] = (f4){0,0,0,0}; acc[h][1] = (f4){0,0,0,0}; }
            {
                const unsigned short* bp0 = w2t + (size_t)(nb +      mp)*256 + q*8;
                const unsigned short* bp1 = w2t + (size_t)(nb + 16 + mp)*256 + q*8;
                bf8 bb0 = *(const bf8*)bp0, bb1 = *(const bf8*)bp1;
                #pragma unroll
                for (int k0 = 0; k0 < 256; k0 += 32) {
                    bf8 n0 = bb0, n1 = bb1;
                    if (k0 + 32 < 256) { n0 = *(const bf8*)(bp0 + k0 + 32); n1 = *(const bf8*)(bp1 + k0 + 32); }
                    #pragma unroll
                    for (int h = 0; h < 4; ++h) {
                        bf8 aa = *(const bf8*)&hbuf[(h*16 + mp)*264 + k0 + q*8];
                        acc[h][0] = MFMA(aa, bb0, acc[h][0]);
                        acc[h][1] = MFMA(aa, bb1, acc[h][1]);
                    }
                    bb0 = n0; bb1 = n1;
                }
            }
            {
                float bias0 = b2p[nb + mp], bias1 = b2p[nb + 16 + mp];
                float w30   = w3p[nb + mp], w31   = w3p[nb + 16 + mp];
                float qp[4][4] = {{0,0,0,0},{0,0,0,0},{0,0,0,0},{0,0,0,0}};
                #pragma unroll
                for (int h = 0; h < 4; ++h) {
                    #pragma unroll
                    for (int r = 0; r < 4; ++r) {
                        float v0 = acc[h][0][r] + bias0;
                        float v1 = acc[h][1][r] + bias1;
                        bool p0 = v0 > 0.f, p1 = v1 > 0.f;
                        unsigned long long bal0 = __ballot(p0);
                        unsigned long long bal1 = __ballot(p1);
                        if (mp == 0) {
                            unsigned w = (unsigned)((bal0 >> (q*16)) & 0xFFFFull)
                                       | (((unsigned)((bal1 >> (q*16)) & 0xFFFFull)) << 16);
                            maskS[net][1][h*16 + q*4 + r][wv] = w;
                        }
                        qp[h][r] += (p0 ? v0 * w30 : 0.f) + (p1 ? v1 * w31 : 0.f);
                    }
                }
                #pragma unroll
                for (int d = 1; d < 16; d <<= 1)
                    #pragma unroll
                    for (int h = 0; h < 4; ++h)
                        #pragma unroll
                        for (int r = 0; r < 4; ++r)
                            qp[h][r] += __shfl_xor(qp[h][r], d, 64);
                if (mp == 0) {
                    #pragma unroll
                    for (int h = 0; h < 4; ++h)
                        #pragma unroll
                        for (int r = 0; r < 4; ++r)
                            qpart[net][wv][h*16 + q*4 + r] = qp[h][r];
                }
            }
            __syncthreads();
        }

        // ======= argmin =======
        if (t < 64) {
            float q0 = b3a[0], q1 = b3b[0];
            #pragma unroll
            for (int w = 0; w < 8; ++w) { q0 += qpart[0][w][t]; q1 += qpart[1][w][t]; }
            winsS[t] = (q0 <= q1) ? 0 : 1;
        }
        __syncthreads();

        // ============ backward both nets + score ============
        for (int net = 0; net < 2; ++net) {
            const unsigned short* w2c = ws + OW2C(net);   // w3 pre-folded

            f4 acc[4][2];
            #pragma unroll
            for (int h = 0; h < 4; ++h) { acc[h][0] = (f4){0,0,0,0}; acc[h][1] = (f4){0,0,0,0}; }
            int win[4];
            #pragma unroll
            for (int h = 0; h < 4; ++h) win[h] = (winsS[h*16 + mp] == net);
            {
                const unsigned short* bp0 = w2c + (size_t)(nb +      mp)*256 + q*8;
                const unsigned short* bp1 = w2c + (size_t)(nb + 16 + mp)*256 + q*8;
                bf8 bb0 = *(const bf8*)bp0, bb1 = *(const bf8*)bp1;
                #pragma unroll
                for (int k0 = 0; k0 < 256; k0 += 32) {
                    bf8 n0 = bb0, n1 = bb1;
                    if (k0 + 32 < 256) { n0 = *(const bf8*)(bp0 + k0 + 32); n1 = *(const bf8*)(bp1 + k0 + 32); }
                    #pragma unroll
                    for (int h = 0; h < 4; ++h) {
                        unsigned bits = win[h] ? ((maskS[net][1][h*16 + mp][k0 >> 5] >> (q*8)) & 0xFFu) : 0u;
                        uint2 lo = lutE[bits & 15u];      // conflict-free gather (broadcast/32-bank)
                        uint2 hi = lutE[bits >> 4];
                        u4 mw; mw[0] = lo.x; mw[1] = lo.y; mw[2] = hi.x; mw[3] = hi.y;
                        bf8 aa = __builtin_bit_cast(bf8, mw);
                        acc[h][0] = MFMA(aa, bb0, acc[h][0]);
                        acc[h][1] = MFMA(aa, bb1, acc[h][1]);
                    }
                    bb0 = n0; bb1 = n1;
                }
            }
            #pragma unroll
            for (int h = 0; h < 4; ++h) {
                #pragma unroll
                for (int s = 0; s < 2; ++s) {
                    int col = nb + s*16 + mp;
                    #pragma unroll
                    for (int r = 0; r < 4; ++r) {
                        int row = h*16 + q*4 + r;
                        bool on = (maskS[net][0][row][col >> 5] >> (col & 31)) & 1u;
                        hbuf[row*264 + col] = f2bfT(on ? acc[h][s][r] : 0.f);
                    }
                }
            }
            __syncthreads();
            // score: wave -> (m-tile, col-half)
            {
                int mt = wv & 3, ch = wv >> 2;
                const unsigned short* w1x = ws + OW1X(net);
                const unsigned short* bp  = w1x + (size_t)(ch*16 + mp)*256 + q*8;
                f4 sa = (f4){0,0,0,0};
                bf8 bx = *(const bf8*)bp;
                #pragma unroll
                for (int k0 = 0; k0 < 256; k0 += 32) {
                    bf8 nx = bx;
                    if (k0 + 32 < 256) nx = *(const bf8*)(bp + k0 + 32);
                    bf8 aa = *(const bf8*)&hbuf[(mt*16 + mp)*264 + k0 + q*8];
                    sa = MFMA(aa, bx, sa);
                    bx = nx;
                }
                int colD = ch*16 + mp;
                if (colD < 20) {
                    #pragma unroll
                    for (int r = 0; r < 4; ++r) {
                        int row = mt*16 + q*4 + r;
                        if (net == 0) scoreS[row*21 + colD]  = sa[r];
                        else          scoreS[row*21 + colD] += sa[r];
                    }
                }
            }
            __syncthreads();
        }

        // ================= RBF via MFMA =================
        // P1: shadows (S, S^T, X^T bf16), norms (from bf16 X), diag terms
        if (t < 64) {
            int st = t >> 5;
            float nrm = 0.f, dg = 0.f;
            #pragma unroll
            for (int d = 0; d < 20; ++d) {
                float xb = bf2f(A0s[t*A0LD + 64 + d]);
                nrm += xb * xb;
                float sv = scoreS[t*21 + d];
                float xv = Xm[t*20 + d];
                dg += xv * sv;
                short sb = f2bfT(sv);
                SBs[t*40 + d] = sb;
                STbS[st*1280 + d*40 + (t & 31)] = sb;
                XTbS[st*1280 + d*40 + (t & 31)] = f2bfT(xv);
            }
            #pragma unroll
            for (int d = 20; d < 32; ++d) SBs[t*40 + d] = 0;
            normsS[t] = nrm;
            diagS[t]  = dg;
        }
        __syncthreads();

        // P2: d2s = n_i + n_j - 2*(X X^T)_ij   and   GS = X S^T  (one tile per wave)
        {
            int stw = wv >> 2, mt = (wv >> 1) & 1, nt = wv & 1;
            bf8 aa  = *(const bf8*)&A0s[(stw*32 + mt*16 + mp)*A0LD + 64 + q*8];
            bf8 bbx = *(const bf8*)&A0s[(stw*32 + nt*16 + mp)*A0LD + 64 + q*8];
            bf8 bbs = *(const bf8*)&SBs[(stw*32 + nt*16 + mp)*40 + q*8];
            f4 gx = MFMA(aa, bbx, ((f4){0,0,0,0}));
            f4 gs = MFMA(aa, bbs, ((f4){0,0,0,0}));
            int jl = nt*16 + mp;
            float nj = normsS[stw*32 + jl];
            #pragma unroll
            for (int r = 0; r < 4; ++r) {
                int il = mt*16 + q*4 + r;
                d2sF[stw*1152 + il*36 + jl] = normsS[stw*32 + il] + nj - 2.f*gx[r];
                GSF [stw*1152 + il*36 + jl] = gs[r];
            }
        }
        __syncthreads();

        // P3: waves 0-1 sort for median (masks no longer need zeroing; other waves idle)
        if (wv < 2) {
            const float* base = d2sF + wv*1152;
            float v[8];
            #pragma unroll
            for (int i = 0; i < 8; ++i) {
                int e = lane*8 + i;
                v[i] = (e < 496) ? base[lutI[e]*36 + lutJ[e]] : 3.4e38f;
            }
            for (int k = 2; k <= 512; k <<= 1) {
                for (int jj = k >> 1; jj >= 8; jj >>= 1) {
                    int lm = jj >> 3;
                    #pragma unroll
                    for (int i = 0; i < 8; ++i) {
                        float w = __shfl_xor(v[i], lm, 64);
                        int p = lane*8 + i;
                        bool takeMin = (((p & k) == 0) == ((p & jj) == 0));
                        v[i] = takeMin ? fminf(v[i], w) : fmaxf(v[i], w);
                    }
                }
                int jj0 = (k >> 1) < 4 ? (k >> 1) : 4;
                for (int jj = jj0; jj >= 1; jj >>= 1) {
                    #pragma unroll
                    for (int i = 0; i < 8; ++i) {
                        if ((i & jj) == 0) {
                            int i2 = i | jj;
                            int p = lane*8 + i;
                            bool up = ((p & k) == 0);
                            float x = v[i], y = v[i2];
                            float mn = fminf(x, y), mx = fmaxf(x, y);
                            v[i] = up ? mn : mx; v[i2] = up ? mx : mn;
                        }
                    }
                }
            }
            if (lane == 29) med2[wv*2 + 0] = v[7];   // sorted index 239
            if (lane == 30) med2[wv*2 + 1] = v[0];   // sorted index 240
        }
        __syncthreads();

        // P4: K = exp(-gamma d2s) -> Kb bf16; fused logp row-sums + rowK (vectorized)
        {
            int i = t >> 3, stw = i >> 5, il = i & 31, j0 = (t & 7) * 4;
            float medv = 0.5f * (med2[stw*2] + med2[stw*2 + 1]);
            float gam  = 1.f / (2.f * (medv / (2.f * LOG33)) + 1e-8f);
            f4 d2 = *(const f4*)&d2sF[stw*1152 + il*36 + j0];
            f4 gs = *(const f4*)&GSF [stw*1152 + il*36 + j0];
            f4 dg = *(const f4*)&diagS[stw*32 + j0];
            float K0 = expf(-gam * d2[0]), K1 = expf(-gam * d2[1]);
            float K2 = expf(-gam * d2[2]), K3 = expf(-gam * d2[3]);
            s4b kb; kb[0] = f2bfT(K0); kb[1] = f2bfT(K1); kb[2] = f2bfT(K2); kb[3] = f2bfT(K3);
            *(s4b*)&KbS[stw*1280 + il*40 + j0] = kb;
            float sK   = K0 + K1 + K2 + K3;
            float sKGS = K0*gs[0] + K1*gs[1] + K2*gs[2] + K3*gs[3];
            float sKd2 = K0*d2[0] + K1*d2[1] + K2*d2[2] + K3*d2[3];
            float sKdg = K0*dg[0] + K1*dg[1] + K2*dg[2] + K3*dg[3];
            #pragma unroll
            for (int d = 1; d < 8; d <<= 1) {
                sK   += __shfl_xor(sK,   d, 64);
                sKGS += __shfl_xor(sKGS, d, 64);
                sKd2 += __shfl_xor(sKd2, d, 64);
                sKdg += __shfl_xor(sKdg, d, 64);
            }
            if ((t & 7) == 0) {
                rowKS[i] = sK;
                float sdots = sKGS - sKdg;                       // sum_j K*dots
                float ssum  = -2.f*gam*sdots
                              - 2.f*gam*(2.f*gam*sKd2 - 20.f*(sK - 1.f));
                logps[i] -= LRC * (ssum * (1.f/32.f));
            }
        }
        __syncthreads();

        // P5: phi = (K@S + 2g(x*rowK - K@X))/32 ; X += LR*phi  (one (m,n) tile per wave)
        {
            int stw = wv >> 2, mt = (wv >> 1) & 1, nt = wv & 1;
            float medv = 0.5f * (med2[stw*2] + med2[stw*2 + 1]);
            float gam  = 1.f / (2.f * (medv / (2.f * LOG33)) + 1e-8f);
            bf8 aa  = *(const bf8*)&KbS [stw*1280 + (mt*16 + mp)*40 + q*8];
            bf8 b1v = *(const bf8*)&STbS[stw*1280 + (nt*16 + mp)*40 + q*8];
            bf8 b2v = *(const bf8*)&XTbS[stw*1280 + (nt*16 + mp)*40 + q*8];
            f4 ks = MFMA(aa, b1v, ((f4){0,0,0,0}));
            f4 kx = MFMA(aa, b2v, ((f4){0,0,0,0}));
            int dd = nt*16 + mp;
            if (dd < 20) {
                #pragma unroll
                for (int r = 0; r < 4; ++r) {
                    int gi = stw*32 + mt*16 + q*4 + r;
                    float xi  = Xm[gi*20 + dd];
                    float phi = (ks[r] + 2.f*gam*(xi*rowKS[gi] - kx[r])) * (1.f/32.f);
                    float nx  = xi + LRC * phi;
                    Xm[gi*20 + dd] = nx;
                    A0s[gi*A0LD + 64 + dd] = f2bfT(nx);
                }
            }
        }
        __syncthreads();
    } // steps

    // ================= epilogue =================
    for (int p = t; p < 64*20; p += 512) {
        int i = p / 20, d = p - i*20;
        out[(b*64 + i)*20 + d] = tanhf(Xm[p]);
    }
    if (t < 64) {
        float lt = 0.f, s0 = 0.f;
        for (int d = 0; d < 20; ++d) {
            float a  = Xm[t*20 + d];
            float x  = -2.f * a;
            float sp = fmaxf(x, 0.f) + log1pf(expf(-fabsf(x)));
            lt -= 2.f * (0.69314718056f - a - sp);
            float v = a0g[(b*64 + t)*20 + d];
            s0 += v * v;
        }
        qvS[t] = -18.3787706641f - 0.5f*s0 + logps[t] + lt;
    }
    __syncthreads();
    if (t < 2) {
        float s = 0.f;
        for (int i = 0; i < 32; ++i) s += qvS[t*32 + i];
        out[1024*32*20 + b*2 + t] = s * (1.f/32.f);
    }
}

extern "C" void kernel_launch(void* const* d_in, const int* in_sizes, int n_in,
                              void* d_out, int out_size, void* d_ws, size_t ws_size,
                              hipStream_t stream) {
    unsigned short* ws = (unsigned short*)d_ws;
    prep_weights<<<(WS_ELEMS + 255)/256, 256, 0, stream>>>(
        (const float*)d_in[2],  (const float*)d_in[4],  (const float*)d_in[6],
        (const float*)d_in[8],  (const float*)d_in[10], (const float*)d_in[12], ws);
    svgd_main<<<NBLK, 512, 0, stream>>>(
        (const float*)d_in[0],  (const float*)d_in[1],
        (const float*)d_in[3],  (const float*)d_in[5],  (const float*)d_in[7],
        (const float*)d_in[9],  (const float*)d_in[11], (const float*)d_in[13],
        (const float*)d_in[6],  (const float*)d_in[12],
        ws, (float*)d_out);
}

// Round 2
// 488.518 us; speedup vs baseline: 1.6652x; 1.6652x over previous
//
#include <hip/hip_runtime.h>
#include <math.h>

#define NPART 32
#define ADIM  20
#define ODIM  64
#define HID   256
#define NSTEPS 5
#define LRC   0.1f
#define NBLK  512     // 2 states per block
#define LOG33 3.4965075614664802f
#define A0LD  104     // A0s row stride in shorts: 52 words == 20 mod 32 -> 2-way (free)

typedef short bf8 __attribute__((ext_vector_type(8)));   // 8 bf16 (4 VGPRs)
typedef short s4b __attribute__((ext_vector_type(4)));   // 4 bf16 packed store
typedef float f4  __attribute__((ext_vector_type(4)));   // MFMA C/D
typedef unsigned u4 __attribute__((ext_vector_type(4)));

// workspace layout (bf16 element offsets)
#define OW1T(n) ((n)*24576)             // [256 n][96 k]   w1^T, k-pad 84->96 (fwd L1 B)
#define OW2T(n) (49152 + (n)*65536)     // [256 n][256 k]  w2^T (fwd L2 B)
#define OW2C(n) (180224 + (n)*65536)    // w2 raw rows with w3 folded: w2[n1][k]*w3[k] (bwd dh1 B)
#define OW1X(n) (311296 + (n)*8192)     // [32 d][256 n]   w1 act-rows (score B)
#define WS_ELEMS 327680

__device__ __forceinline__ short f2bf(float x) {          // RNE f32->bf16 (prep only)
    unsigned u = __float_as_uint(x);
    u += 0x7FFFu + ((u >> 16) & 1u);
    return (short)(u >> 16);
}
__device__ __forceinline__ short f2bfT(float x) {         // truncating f32->bf16 (fast)
    return (short)(__float_as_uint(x) >> 16);
}
__device__ __forceinline__ float bf2f(short s) {
    return __uint_as_float(((unsigned)(unsigned short)s) << 16);
}

#define MFMA(a,b,c) __builtin_amdgcn_mfma_f32_16x16x32_bf16((a),(b),(c),0,0,0)

// ---------- prep: build bf16 weight images in ws ----------
__global__ void prep_weights(const float* __restrict__ w1a, const float* __restrict__ w2a,
                             const float* __restrict__ w3a, const float* __restrict__ w1b,
                             const float* __restrict__ w2b, const float* __restrict__ w3b,
                             unsigned short* __restrict__ ws)
{
    int idx = blockIdx.x * 256 + threadIdx.x;
    if (idx >= WS_ELEMS) return;
    float val;
    if (idx < 49152) {
        int net = idx / 24576, rem = idx % 24576;
        int n = rem / 96, k = rem % 96;
        const float* w1 = net ? w1b : w1a;
        val = (k < 84) ? w1[k*256 + n] : 0.f;
    } else if (idx < 180224) {
        int t2 = idx - 49152; int net = t2 / 65536, rem = t2 % 65536;
        int n = rem / 256, k = rem % 256;
        const float* w2 = net ? w2b : w2a;
        val = w2[k*256 + n];
    } else if (idx < 311296) {
        int t2 = idx - 180224; int net = t2 / 65536, rem = t2 % 65536;
        const float* w2 = net ? w2b : w2a;
        const float* w3 = net ? w3b : w3a;
        val = w2[rem] * w3[rem % 256];            // fold w3 into bwd w2 rows (fp32 product)
    } else {
        int t2 = idx - 311296; int net = t2 / 8192, rem = t2 % 8192;
        int d = rem / 256, n = rem % 256;
        const float* w1 = net ? w1b : w1a;
        val = (d < 20) ? w1[(64 + d)*256 + n] : 0.f;
    }
    ws[idx] = (unsigned short)f2bf(val);
}

// ---------- main: 2 states per block, 512 threads ----------
__global__ void __launch_bounds__(512, 4)
svgd_main(const float* __restrict__ obs,  const float* __restrict__ a0g,
          const float* __restrict__ b1a,  const float* __restrict__ b2a, const float* __restrict__ b3a,
          const float* __restrict__ b1b,  const float* __restrict__ b2b, const float* __restrict__ b3b,
          const float* __restrict__ w3af, const float* __restrict__ w3bf,
          const unsigned short* __restrict__ ws, float* __restrict__ out)
{
    __shared__ __align__(16) short A0s[64*A0LD];    // [obs|X|pad] bf16, 2 states stacked
    __shared__ __align__(16) short hbuf[64*264];    // h1/g1 bf16; RBF shadows alias (see below)
    __shared__ unsigned maskS[2][2][64][8];         // relu bitmasks (fully overwritten each step)
    __shared__ float Xm[64*20];                     // fp32 master particles
    __shared__ float scoreS[64*21];
    __shared__ float qpart[2][8][64];
    __shared__ int   winsS[64];
    __shared__ float logps[64];
    __shared__ unsigned short lutI[496], lutJ[496];
    __shared__ float med2[4];                        // [state][2]
    __shared__ float qvS[64];
    __shared__ float normsS[64], rowKS[64];
    __shared__ __align__(16) float diagS[64];

    // hbuf alias map (short offsets), lifetimes confined between "g1 dead" and "next h1":
    // d2sF  [2][32 rows][36 f32]  shorts     0.. 4607   (w P2, r P3/P4)
    // GSF   [2][32 rows][36 f32]  shorts  4608.. 9215   (w P2, r P4)
    // SBs   [64 rows][40]  bf16   shorts  9216..11775   (w P1, r P2)  -- dead after P2
    // KbS   [2][32][40]    bf16   shorts  9216..11775   (w P4, r P5)  -- aliases SBs
    // STbS  [2][32 dd][40 j]      shorts 11776..14335   (w P1, r P5)
    // XTbS  [2][32 dd][40 j]      shorts 14336..16895   (w P1, r P5)
    float* d2sF = (float*)hbuf;
    float* GSF  = ((float*)hbuf) + 2304;
    short* SBs  = hbuf + 9216;
    short* KbS  = hbuf + 9216;
    short* STbS = hbuf + 11776;
    short* XTbS = hbuf + 14336;

    const int t = threadIdx.x, b = blockIdx.x;
    const int lane = t & 63, wv = t >> 6;           // 8 waves
    const int q = lane >> 4, mp = lane & 15;
    const int nb = wv * 32;                          // 32-col slice of the 256-wide GEMMs

    // ---- init ----
    for (int p = t; p < 64*ODIM; p += 512) {
        int i = p >> 6, d = p & 63;
        A0s[i*A0LD + d] = f2bfT(obs[(b*64 + i)*ODIM + d]);
    }
    for (int p = t; p < 64*ADIM; p += 512) {
        int i = p / 20, d = p - i*20;
        float v = a0g[(b*64 + i)*20 + d];
        Xm[p] = v;
        A0s[i*A0LD + 64 + d] = f2bfT(v);
    }
    for (int p = t; p < 64*12; p += 512) { int i = p/12, d = p - i*12; A0s[i*A0LD + 84 + d] = 0; }
    if (t < 496) {
        int i_ = 0, rem = t;
        while (rem >= 31 - i_) { rem -= 31 - i_; ++i_; }
        lutI[t] = (unsigned short)i_; lutJ[t] = (unsigned short)(i_ + 1 + rem);
    }
    if (t < 64) logps[t] = 0.f;
    __syncthreads();

    for (int step = 0; step < NSTEPS; ++step) {
        // ================= forward both nets =================
        for (int net = 0; net < 2; ++net) {
            const unsigned short* w1t = ws + OW1T(net);
            const unsigned short* w2t = ws + OW2T(net);
            const float* b1p = net ? b1b : b1a;
            const float* b2p = net ? b2b : b2a;
            const float* w3p = net ? w3bf : w3af;

            // ---- L1: [64 x 96] @ w1t -> h1 ----
            f4 acc[4][2];
            #pragma unroll
            for (int h = 0; h < 4; ++h) { acc[h][0] = (f4){0,0,0,0}; acc[h][1] = (f4){0,0,0,0}; }
            {
                const unsigned short* bp0 = w1t + (size_t)(nb +      mp)*96 + q*8;
                const unsigned short* bp1 = w1t + (size_t)(nb + 16 + mp)*96 + q*8;
                bf8 bb0 = *(const bf8*)bp0, bb1 = *(const bf8*)bp1;
                #pragma unroll
                for (int k0 = 0; k0 < 96; k0 += 32) {
                    bf8 n0 = bb0, n1 = bb1;
                    if (k0 + 32 < 96) { n0 = *(const bf8*)(bp0 + k0 + 32); n1 = *(const bf8*)(bp1 + k0 + 32); }
                    #pragma unroll
                    for (int h = 0; h < 4; ++h) {
                        bf8 aa = *(const bf8*)&A0s[(h*16 + mp)*A0LD + k0 + q*8];
                        acc[h][0] = MFMA(aa, bb0, acc[h][0]);
                        acc[h][1] = MFMA(aa, bb1, acc[h][1]);
                    }
                    bb0 = n0; bb1 = n1;
                }
            }
            {
                float bias0 = b1p[nb + mp], bias1 = b1p[nb + 16 + mp];
                #pragma unroll
                for (int h = 0; h < 4; ++h) {
                    #pragma unroll
                    for (int r = 0; r < 4; ++r) {
                        float v0 = acc[h][0][r] + bias0;
                        float v1 = acc[h][1][r] + bias1;
                        bool p0 = v0 > 0.f, p1 = v1 > 0.f;
                        unsigned long long bal0 = __ballot(p0);
                        unsigned long long bal1 = __ballot(p1);
                        int row = h*16 + q*4 + r;
                        hbuf[row*264 + nb +      mp] = f2bfT(p0 ? v0 : 0.f);
                        hbuf[row*264 + nb + 16 + mp] = f2bfT(p1 ? v1 : 0.f);
                        if (mp == 0) {
                            unsigned w = (unsigned)((bal0 >> (q*16)) & 0xFFFFull)
                                       | (((unsigned)((bal1 >> (q*16)) & 0xFFFFull)) << 16);
                            maskS[net][0][row][wv] = w;       // single writer, no atomic
                        }
                    }
                }
            }
            __syncthreads();

            // ---- L2: h1 @ w2t (w3/q fused, no h2 materialization) ----
            #pragma unroll
            for (int h = 0; h < 4; ++h) { acc[h][0] = (f4){0,0,0,0}; acc[h][1] = (f4){0,0,0,0}; }
            {
                const unsigned short* bp0 = w2t + (size_t)(nb +      mp)*256 + q*8;
                const unsigned short* bp1 = w2t + (size_t)(nb + 16 + mp)*256 + q*8;
                bf8 bb0 = *(const bf8*)bp0, bb1 = *(const bf8*)bp1;
                #pragma unroll
                for (int k0 = 0; k0 < 256; k0 += 32) {
                    bf8 n0 = bb0, n1 = bb1;
                    if (k0 + 32 < 256) { n0 = *(const bf8*)(bp0 + k0 + 32); n1 = *(const bf8*)(bp1 + k0 + 32); }
                    #pragma unroll
                    for (int h = 0; h < 4; ++h) {
                        bf8 aa = *(const bf8*)&hbuf[(h*16 + mp)*264 + k0 + q*8];
                        acc[h][0] = MFMA(aa, bb0, acc[h][0]);
                        acc[h][1] = MFMA(aa, bb1, acc[h][1]);
                    }
                    bb0 = n0; bb1 = n1;
                }
            }
            {
                float bias0 = b2p[nb + mp], bias1 = b2p[nb + 16 + mp];
                float w30   = w3p[nb + mp], w31   = w3p[nb + 16 + mp];
                float qp[4][4] = {{0,0,0,0},{0,0,0,0},{0,0,0,0},{0,0,0,0}};
                #pragma unroll
                for (int h = 0; h < 4; ++h) {
                    #pragma unroll
                    for (int r = 0; r < 4; ++r) {
                        float v0 = acc[h][0][r] + bias0;
                        float v1 = acc[h][1][r] + bias1;
                        bool p0 = v0 > 0.f, p1 = v1 > 0.f;
                        unsigned long long bal0 = __ballot(p0);
                        unsigned long long bal1 = __ballot(p1);
                        if (mp == 0) {
                            unsigned w = (unsigned)((bal0 >> (q*16)) & 0xFFFFull)
                                       | (((unsigned)((bal1 >> (q*16)) & 0xFFFFull)) << 16);
                            maskS[net][1][h*16 + q*4 + r][wv] = w;
                        }
                        qp[h][r] += (p0 ? v0 * w30 : 0.f) + (p1 ? v1 * w31 : 0.f);
                    }
                }
                #pragma unroll
                for (int d = 1; d < 16; d <<= 1)
                    #pragma unroll
                    for (int h = 0; h < 4; ++h)
                        #pragma unroll
                        for (int r = 0; r < 4; ++r)
                            qp[h][r] += __shfl_xor(qp[h][r], d, 64);
                if (mp == 0) {
                    #pragma unroll
                    for (int h = 0; h < 4; ++h)
                        #pragma unroll
                        for (int r = 0; r < 4; ++r)
                            qpart[net][wv][h*16 + q*4 + r] = qp[h][r];
                }
            }
            __syncthreads();
        }

        // ======= argmin =======
        if (t < 64) {
            float q0 = b3a[0], q1 = b3b[0];
            #pragma unroll
            for (int w = 0; w < 8; ++w) { q0 += qpart[0][w][t]; q1 += qpart[1][w][t]; }
            winsS[t] = (q0 <= q1) ? 0 : 1;
        }
        __syncthreads();

        // ============ backward both nets + score ============
        for (int net = 0; net < 2; ++net) {
            const unsigned short* w2c = ws + OW2C(net);   // w3 pre-folded

            f4 acc[4][2];
            #pragma unroll
            for (int h = 0; h < 4; ++h) { acc[h][0] = (f4){0,0,0,0}; acc[h][1] = (f4){0,0,0,0}; }
            int win[4];
            #pragma unroll
            for (int h = 0; h < 4; ++h) win[h] = (winsS[h*16 + mp] == net);
            {
                const unsigned short* bp0 = w2c + (size_t)(nb +      mp)*256 + q*8;
                const unsigned short* bp1 = w2c + (size_t)(nb + 16 + mp)*256 + q*8;
                bf8 bb0 = *(const bf8*)bp0, bb1 = *(const bf8*)bp1;
                #pragma unroll
                for (int k0 = 0; k0 < 256; k0 += 32) {
                    bf8 n0 = bb0, n1 = bb1;
                    if (k0 + 32 < 256) { n0 = *(const bf8*)(bp0 + k0 + 32); n1 = *(const bf8*)(bp1 + k0 + 32); }
                    #pragma unroll
                    for (int h = 0; h < 4; ++h) {
                        // mask bits -> bf16 {0,1.0} halves via register ALU (no LDS, no LUT)
                        unsigned bits = win[h] ? ((maskS[net][1][h*16 + mp][k0 >> 5] >> (q*8)) & 0xFFu) : 0u;
                        u4 mw;
                        mw[0] = ((bits &   1u) ? 0x3F80u : 0u) | ((bits &   2u) ? 0x3F800000u : 0u);
                        mw[1] = ((bits &   4u) ? 0x3F80u : 0u) | ((bits &   8u) ? 0x3F800000u : 0u);
                        mw[2] = ((bits &  16u) ? 0x3F80u : 0u) | ((bits &  32u) ? 0x3F800000u : 0u);
                        mw[3] = ((bits &  64u) ? 0x3F80u : 0u) | ((bits & 128u) ? 0x3F800000u : 0u);
                        bf8 aa = __builtin_bit_cast(bf8, mw);
                        acc[h][0] = MFMA(aa, bb0, acc[h][0]);
                        acc[h][1] = MFMA(aa, bb1, acc[h][1]);
                    }
                    bb0 = n0; bb1 = n1;
                }
            }
            #pragma unroll
            for (int h = 0; h < 4; ++h) {
                #pragma unroll
                for (int s = 0; s < 2; ++s) {
                    int col = nb + s*16 + mp;
                    #pragma unroll
                    for (int r = 0; r < 4; ++r) {
                        int row = h*16 + q*4 + r;
                        bool on = (maskS[net][0][row][col >> 5] >> (col & 31)) & 1u;
                        hbuf[row*264 + col] = f2bfT(on ? acc[h][s][r] : 0.f);
                    }
                }
            }
            __syncthreads();
            // score: wave -> (m-tile, col-half)
            {
                int mt = wv & 3, ch = wv >> 2;
                const unsigned short* w1x = ws + OW1X(net);
                const unsigned short* bp  = w1x + (size_t)(ch*16 + mp)*256 + q*8;
                f4 sa = (f4){0,0,0,0};
                bf8 bx = *(const bf8*)bp;
                #pragma unroll
                for (int k0 = 0; k0 < 256; k0 += 32) {
                    bf8 nx = bx;
                    if (k0 + 32 < 256) nx = *(const bf8*)(bp + k0 + 32);
                    bf8 aa = *(const bf8*)&hbuf[(mt*16 + mp)*264 + k0 + q*8];
                    sa = MFMA(aa, bx, sa);
                    bx = nx;
                }
                int colD = ch*16 + mp;
                if (colD < 20) {
                    #pragma unroll
                    for (int r = 0; r < 4; ++r) {
                        int row = mt*16 + q*4 + r;
                        if (net == 0) scoreS[row*21 + colD]  = sa[r];
                        else          scoreS[row*21 + colD] += sa[r];
                    }
                }
            }
            __syncthreads();
        }

        // ================= RBF via MFMA =================
        // P1: shadows (S, S^T, X^T bf16), norms (from bf16 X), diag terms
        if (t < 64) {
            int st = t >> 5;
            float nrm = 0.f, dg = 0.f;
            #pragma unroll
            for (int d = 0; d < 20; ++d) {
                float xb = bf2f(A0s[t*A0LD + 64 + d]);
                nrm += xb * xb;
                float sv = scoreS[t*21 + d];
                float xv = Xm[t*20 + d];
                dg += xv * sv;
                short sb = f2bfT(sv);
                SBs[t*40 + d] = sb;
                STbS[st*1280 + d*40 + (t & 31)] = sb;
                XTbS[st*1280 + d*40 + (t & 31)] = f2bfT(xv);
            }
            #pragma unroll
            for (int d = 20; d < 32; ++d) SBs[t*40 + d] = 0;
            normsS[t] = nrm;
            diagS[t]  = dg;
        }
        __syncthreads();

        // P2: d2s = n_i + n_j - 2*(X X^T)_ij   and   GS = X S^T  (one tile per wave)
        {
            int stw = wv >> 2, mt = (wv >> 1) & 1, nt = wv & 1;
            bf8 aa  = *(const bf8*)&A0s[(stw*32 + mt*16 + mp)*A0LD + 64 + q*8];
            bf8 bbx = *(const bf8*)&A0s[(stw*32 + nt*16 + mp)*A0LD + 64 + q*8];
            bf8 bbs = *(const bf8*)&SBs[(stw*32 + nt*16 + mp)*40 + q*8];
            f4 gx = MFMA(aa, bbx, ((f4){0,0,0,0}));
            f4 gs = MFMA(aa, bbs, ((f4){0,0,0,0}));
            int jl = nt*16 + mp;
            float nj = normsS[stw*32 + jl];
            #pragma unroll
            for (int r = 0; r < 4; ++r) {
                int il = mt*16 + q*4 + r;
                d2sF[stw*1152 + il*36 + jl] = normsS[stw*32 + il] + nj - 2.f*gx[r];
                GSF [stw*1152 + il*36 + jl] = gs[r];
            }
        }
        __syncthreads();

        // P3: waves 0-1 sort for median
        if (wv < 2) {
            const float* base = d2sF + wv*1152;
            float v[8];
            #pragma unroll
            for (int i = 0; i < 8; ++i) {
                int e = lane*8 + i;
                v[i] = (e < 496) ? base[lutI[e]*36 + lutJ[e]] : 3.4e38f;
            }
            for (int k = 2; k <= 512; k <<= 1) {
                for (int jj = k >> 1; jj >= 8; jj >>= 1) {
                    int lm = jj >> 3;
                    #pragma unroll
                    for (int i = 0; i < 8; ++i) {
                        float w = __shfl_xor(v[i], lm, 64);
                        int p = lane*8 + i;
                        bool takeMin = (((p & k) == 0) == ((p & jj) == 0));
                        v[i] = takeMin ? fminf(v[i], w) : fmaxf(v[i], w);
                    }
                }
                int jj0 = (k >> 1) < 4 ? (k >> 1) : 4;
                for (int jj = jj0; jj >= 1; jj >>= 1) {
                    #pragma unroll
                    for (int i = 0; i < 8; ++i) {
                        if ((i & jj) == 0) {
                            int i2 = i | jj;
                            int p = lane*8 + i;
                            bool up = ((p & k) == 0);
                            float x = v[i], y = v[i2];
                            float mn = fminf(x, y), mx = fmaxf(x, y);
                            v[i] = up ? mn : mx; v[i2] = up ? mx : mn;
                        }
                    }
                }
            }
            if (lane == 29) med2[wv*2 + 0] = v[7];   // sorted index 239
            if (lane == 30) med2[wv*2 + 1] = v[0];   // sorted index 240
        }
        __syncthreads();

        // P4: K = exp(-gamma d2s) -> Kb bf16; fused logp row-sums + rowK (vectorized)
        {
            int i = t >> 3, stw = i >> 5, il = i & 31, j0 = (t & 7) * 4;
            float medv = 0.5f * (med2[stw*2] + med2[stw*2 + 1]);
            float gam  = 1.f / (2.f * (medv / (2.f * LOG33)) + 1e-8f);
            f4 d2 = *(const f4*)&d2sF[stw*1152 + il*36 + j0];
            f4 gs = *(const f4*)&GSF [stw*1152 + il*36 + j0];
            f4 dg = *(const f4*)&diagS[stw*32 + j0];
            float K0 = expf(-gam * d2[0]), K1 = expf(-gam * d2[1]);
            float K2 = expf(-gam * d2[2]), K3 = expf(-gam * d2[3]);
            s4b kb; kb[0] = f2bfT(K0); kb[1] = f2bfT(K1); kb[2] = f2bfT(K2); kb[3] = f2bfT(K3);
            *(s4b*)&KbS[stw*1280 + il*40 + j0] = kb;
            float sK   = K0 + K1 + K2 + K3;
            float sKGS = K0*gs[0] + K1*gs[1] + K2*gs[2] + K3*gs[3];
            float sKd2 = K0*d2[0] + K1*d2[1] + K2*d2[2] + K3*d2[3];
            float sKdg = K0*dg[0] + K1*dg[1] + K2*dg[2] + K3*dg[3];
            #pragma unroll
            for (int d = 1; d < 8; d <<= 1) {
                sK   += __shfl_xor(sK,   d, 64);
                sKGS += __shfl_xor(sKGS, d, 64);
                sKd2 += __shfl_xor(sKd2, d, 64);
                sKdg += __shfl_xor(sKdg, d, 64);
            }
            if ((t & 7) == 0) {
                rowKS[i] = sK;
                float sdots = sKGS - sKdg;                       // sum_j K*dots
                float ssum  = -2.f*gam*sdots
                              - 2.f*gam*(2.f*gam*sKd2 - 20.f*(sK - 1.f));
                logps[i] -= LRC * (ssum * (1.f/32.f));
            }
        }
        __syncthreads();

        // P5: phi = (K@S + 2g(x*rowK - K@X))/32 ; X += LR*phi  (one (m,n) tile per wave)
        {
            int stw = wv >> 2, mt = (wv >> 1) & 1, nt = wv & 1;
            float medv = 0.5f * (med2[stw*2] + med2[stw*2 + 1]);
            float gam  = 1.f / (2.f * (medv / (2.f * LOG33)) + 1e-8f);
            bf8 aa  = *(const bf8*)&KbS [stw*1280 + (mt*16 + mp)*40 + q*8];
            bf8 b1v = *(const bf8*)&STbS[stw*1280 + (nt*16 + mp)*40 + q*8];
            bf8 b2v = *(const bf8*)&XTbS[stw*1280 + (nt*16 + mp)*40 + q*8];
            f4 ks = MFMA(aa, b1v, ((f4){0,0,0,0}));
            f4 kx = MFMA(aa, b2v, ((f4){0,0,0,0}));
            int dd = nt*16 + mp;
            if (dd < 20) {
                #pragma unroll
                for (int r = 0; r < 4; ++r) {
                    int gi = stw*32 + mt*16 + q*4 + r;
                    float xi  = Xm[gi*20 + dd];
                    float phi = (ks[r] + 2.f*gam*(xi*rowKS[gi] - kx[r])) * (1.f/32.f);
                    float nx  = xi + LRC * phi;
                    Xm[gi*20 + dd] = nx;
                    A0s[gi*A0LD + 64 + dd] = f2bfT(nx);
                }
            }
        }
        __syncthreads();
    } // steps

    // ================= epilogue =================
    for (int p = t; p < 64*20; p += 512) {
        int i = p / 20, d = p - i*20;
        out[(b*64 + i)*20 + d] = tanhf(Xm[p]);
    }
    if (t < 64) {
        float lt = 0.f, s0 = 0.f;
        for (int d = 0; d < 20; ++d) {
            float a  = Xm[t*20 + d];
            float x  = -2.f * a;
            float sp = fmaxf(x, 0.f) + log1pf(expf(-fabsf(x)));
            lt -= 2.f * (0.69314718056f - a - sp);
            float v = a0g[(b*64 + t)*20 + d];
            s0 += v * v;
        }
        qvS[t] = -18.3787706641f - 0.5f*s0 + logps[t] + lt;
    }
    __syncthreads();
    if (t < 2) {
        float s = 0.f;
        for (int i = 0; i < 32; ++i) s += qvS[t*32 + i];
        out[1024*32*20 + b*2 + t] = s * (1.f/32.f);
    }
}

extern "C" void kernel_launch(void* const* d_in, const int* in_sizes, int n_in,
                              void* d_out, int out_size, void* d_ws, size_t ws_size,
                              hipStream_t stream) {
    unsigned short* ws = (unsigned short*)d_ws;
    prep_weights<<<(WS_ELEMS + 255)/256, 256, 0, stream>>>(
        (const float*)d_in[2],  (const float*)d_in[4],  (const float*)d_in[6],
        (const float*)d_in[8],  (const float*)d_in[10], (const float*)d_in[12], ws);
    svgd_main<<<NBLK, 512, 0, stream>>>(
        (const float*)d_in[0],  (const float*)d_in[1],
        (const float*)d_in[3],  (const float*)d_in[5],  (const float*)d_in[7],
        (const float*)d_in[9],  (const float*)d_in[11], (const float*)d_in[13],
        (const float*)d_in[6],  (const float*)d_in[12],
        ws, (float*)d_out);
}